// Round 2
// baseline (1074.902 us; speedup 1.0000x reference)
//
#include <hip/hip_runtime.h>

#define B_    32
#define S_    577
#define HID_  768
#define NH_   12
#define HD_   64
#define SPAD  640
#define M_    (B_ * S_)   // 18464 = 577*32 exactly

typedef __attribute__((ext_vector_type(8))) short short8;
typedef __attribute__((ext_vector_type(4))) short short4_;
typedef __attribute__((ext_vector_type(4))) float float4_;

static __device__ __forceinline__ float bf2f(short s) {
    union { float f; unsigned u; } cvt;
    cvt.u = ((unsigned)(unsigned short)s) << 16;
    return cvt.f;
}
static __device__ __forceinline__ short f2bf(float f) {
    union { float f; unsigned u; } cvt;
    cvt.f = f;
    unsigned u = cvt.u;
    unsigned r = u + 0x7FFF + ((u >> 16) & 1);   // RNE; inputs finite fp32
    return (short)(r >> 16);
}

// ---------------------------------------------------------------------------
// W fp32 -> bf16, packed [z][n][k] row-major (3 x 768 x 768)
// ---------------------------------------------------------------------------
__global__ __launch_bounds__(256) void convw_kernel(
    const float* __restrict__ Wq, const float* __restrict__ Wk,
    const float* __restrict__ Wv, short* __restrict__ wbf)
{
    const int z = blockIdx.y;
    const float* W = (z == 0) ? Wq : (z == 1) ? Wk : Wv;
    const size_t idx = ((size_t)blockIdx.x * 256 + threadIdx.x) * 4;
    float4_ f = *(const float4_*)(W + idx);
    short4_ s;
#pragma unroll
    for (int e = 0; e < 4; ++e) s[e] = f2bf(f[e]);
    *(short4_*)(wbf + (size_t)z * (HID_ * HID_) + idx) = s;
}

// ---------------------------------------------------------------------------
// Projection: out = X @ W^T + b (+ optional lateral mix), X fp32 read once per
// (tileM,z), converted to bf16 in LDS, reused across 12 heads.
// grid = (577 tiles of 32 rows, 3 matrices), block 256 (4 waves).
// wave (w&1): row strip 0-15/16-31;  wave (w>>1): heads 0-5 / 6-11.
// q/k stored [B,NH,SPAD,64] bf16; v stored transposed [B,NH,64,SPAD].
// ---------------------------------------------------------------------------
__global__ __launch_bounds__(256) void proj_kernel(
    const float* __restrict__ X,
    const float* __restrict__ bq, const float* __restrict__ bk,
    const float* __restrict__ bv,
    const float* __restrict__ lat, const int* __restrict__ mixw,
    const short* __restrict__ wbf,
    short* __restrict__ qo, short* __restrict__ ko, short* __restrict__ vo)
{
    __shared__ __align__(16) short xt[32][776];   // 768 + 8 pad (bank shift 4/row)
    const int z  = blockIdx.y;
    const int m0 = blockIdx.x * 32;

    // stage X tile: 32x768 fp32 -> bf16 (24576 elems, 24 iters x 256 thr x 4)
#pragma unroll
    for (int j = 0; j < 24; ++j) {
        const int flat = j * 1024 + threadIdx.x * 4;   // float4 never crosses a row
        const int row  = flat / 768;
        const int col  = flat - row * 768;
        float4_ f = *(const float4_*)(X + (size_t)(m0 + row) * HID_ + col);
        short4_ s;
#pragma unroll
        for (int e = 0; e < 4; ++e) s[e] = f2bf(f[e]);
        *(short4_*)(&xt[row][col]) = s;
    }
    __syncthreads();

    const int wave = threadIdx.x >> 6;
    const int lane = threadIdx.x & 63;
    const int quad = lane >> 4;
    const int l16  = lane & 15;
    const int row_off = (wave & 1) * 16;
    const int hbase   = (wave >> 1) * 6;

    const short* wz = wbf + (size_t)z * (HID_ * HID_);
    const float* bb = (z == 0) ? bq : (z == 1) ? bk : bv;
    const int mw = *mixw;

    for (int hh = 0; hh < 6; ++hh) {
        const int h = hbase + hh;
        const int n_base = h * 64;
        float4_ acc[4] = {};
        for (int kk = 0; kk < HID_; kk += 32) {
            short8 a = *(const short8*)(&xt[row_off + l16][kk + quad * 8]);
#pragma unroll
            for (int g = 0; g < 4; ++g) {
                short8 bfr = *(const short8*)(wz + (size_t)(n_base + g * 16 + l16) * HID_
                                              + kk + quad * 8);
                acc[g] = __builtin_amdgcn_mfma_f32_16x16x32_bf16(a, bfr, acc[g], 0, 0, 0);
            }
        }
        // epilogue: C row = quad*4+reg, col = l16
#pragma unroll
        for (int i = 0; i < 4; ++i) {
            const int m = m0 + row_off + quad * 4 + i;      // always < M_
            const unsigned bidx = (unsigned)m / S_;
            const unsigned s    = (unsigned)m - bidx * S_;
#pragma unroll
            for (int g = 0; g < 4; ++g) {
                const int d = g * 16 + l16;
                float val = acc[g][i] + bb[n_base + d];
                if (z == mw)
                    val *= lat[(((size_t)bidx * NH_ + h) * S_ + s) * HD_ + d];
                const short o = f2bf(val);
                if (z == 2) {
                    vo[(((size_t)bidx * NH_ + h) * HD_ + d) * SPAD + s] = o;
                } else {
                    short* dst = (z == 0) ? qo : ko;
                    dst[(((size_t)bidx * NH_ + h) * SPAD + s) * HD_ + d] = o;
                }
            }
        }
    }
}

// ---------------------------------------------------------------------------
// Flash attention: one wave per 16-row q-tile, key chunks of 32.
// grid = (384 bh, 10 qtiles), block 256 (4 waves). fp32 output.
// ---------------------------------------------------------------------------
__global__ __launch_bounds__(256) void attn_kernel(
    const short* __restrict__ q, const short* __restrict__ k,
    const short* __restrict__ vt, float* __restrict__ out)
{
    __shared__ __align__(16) short pbuf[4][16][32];   // per-wave P transpose

    const int bh   = blockIdx.x;
    const int b    = bh / NH_;
    const int h    = bh - b * NH_;
    const int wave = threadIdx.x >> 6;
    const int lane = threadIdx.x & 63;
    const int quad = lane >> 4;
    const int l16  = lane & 15;
    const int q0   = blockIdx.y * 64 + wave * 16;

    const short* qp = q  + (size_t)bh * SPAD * HD_;
    const short* kp = k  + (size_t)bh * SPAD * HD_;
    const short* vp = vt + (size_t)bh * HD_ * SPAD;

    const short8 aq0 = *(const short8*)(qp + (size_t)(q0 + l16) * HD_ + quad * 8);
    const short8 aq1 = *(const short8*)(qp + (size_t)(q0 + l16) * HD_ + 32 + quad * 8);

    float m_i[4], l_i[4];
    float4_ O[4] = {};
#pragma unroll
    for (int i = 0; i < 4; ++i) { m_i[i] = -3.0e38f; l_i[i] = 0.0f; }

    for (int kc = 0; kc < 19; ++kc) {
        const int key0 = kc * 32;

        float4_ sc[2] = {};
#pragma unroll
        for (int g = 0; g < 2; ++g) {
            const short* kr = kp + (size_t)(key0 + g * 16 + l16) * HD_ + quad * 8;
            short8 b0 = *(const short8*)kr;
            short8 b1 = *(const short8*)(kr + 32);
            sc[g] = __builtin_amdgcn_mfma_f32_16x16x32_bf16(aq0, b0, sc[g], 0, 0, 0);
            sc[g] = __builtin_amdgcn_mfma_f32_16x16x32_bf16(aq1, b1, sc[g], 0, 0, 0);
        }

        const bool mask0 = (key0 + l16) >= S_;
        const bool mask1 = (key0 + 16 + l16) >= S_;

        float alpha[4];
#pragma unroll
        for (int i = 0; i < 4; ++i) {
            float s0 = mask0 ? -3.0e38f : sc[0][i] * 0.125f;
            float s1 = mask1 ? -3.0e38f : sc[1][i] * 0.125f;
            float cm = fmaxf(s0, s1);
#pragma unroll
            for (int off = 1; off < 16; off <<= 1)
                cm = fmaxf(cm, __shfl_xor(cm, off));
            const float mn = fmaxf(m_i[i], cm);
            alpha[i] = __expf(m_i[i] - mn);
            m_i[i] = mn;
            const short pb0 = f2bf(__expf(s0 - mn));
            const short pb1 = f2bf(__expf(s1 - mn));
            pbuf[wave][quad * 4 + i][l16]      = pb0;
            pbuf[wave][quad * 4 + i][l16 + 16] = pb1;
            // l_i from ROUNDED p so PV normalization cancels rounding
            float rs = bf2f(pb0) + bf2f(pb1);
#pragma unroll
            for (int off = 1; off < 16; off <<= 1)
                rs += __shfl_xor(rs, off);
            l_i[i] = l_i[i] * alpha[i] + rs;
        }

#pragma unroll
        for (int g = 0; g < 4; ++g) {
#pragma unroll
            for (int i = 0; i < 4; ++i) O[g][i] *= alpha[i];
        }

        const short8 ap = *(const short8*)(&pbuf[wave][l16][quad * 8]);

#pragma unroll
        for (int g = 0; g < 4; ++g) {
            const short* vr = vp + (size_t)(g * 16 + l16) * SPAD + key0 + quad * 8;
            short8 bv = *(const short8*)vr;
            O[g] = __builtin_amdgcn_mfma_f32_16x16x32_bf16(ap, bv, O[g], 0, 0, 0);
        }
    }

#pragma unroll
    for (int i = 0; i < 4; ++i) {
        const int s = q0 + quad * 4 + i;
        if (s >= S_) continue;
        const float inv = 1.0f / l_i[i];
#pragma unroll
        for (int g = 0; g < 4; ++g)
            out[((size_t)b * S_ + s) * HID_ + h * HD_ + g * 16 + l16] = O[g][i] * inv;
    }
}

extern "C" void kernel_launch(void* const* d_in, const int* in_sizes, int n_in,
                              void* d_out, int out_size, void* d_ws, size_t ws_size,
                              hipStream_t stream) {
    (void)in_sizes; (void)n_in; (void)out_size; (void)ws_size;

    const float* X   = (const float*)d_in[0];
    const float* lat = (const float*)d_in[1];
    const float* Wq  = (const float*)d_in[2];
    const float* bq  = (const float*)d_in[3];
    const float* Wk  = (const float*)d_in[4];
    const float* bk  = (const float*)d_in[5];
    const float* Wv  = (const float*)d_in[6];
    const float* bv  = (const float*)d_in[7];
    const int* mixw  = (const int*)d_in[8];
    float* out = (float*)d_out;

    const size_t per = (size_t)B_ * NH_ * SPAD * HD_;   // 15,728,640 elems
    short* qw  = (short*)d_ws;
    short* kw  = qw + per;
    short* vw  = kw + per;
    short* wbf = vw + per;                              // + 1,769,472 elems

    convw_kernel<<<dim3(576, 3), 256, 0, stream>>>(Wq, Wk, Wv, wbf);
    proj_kernel<<<dim3(577, 3), 256, 0, stream>>>(
        X, bq, bk, bv, lat, mixw, wbf, qw, kw, vw);
    attn_kernel<<<dim3(384, 10), 256, 0, stream>>>(qw, kw, vw, out);
}

// Round 3
// 587.016 us; speedup vs baseline: 1.8311x; 1.8311x over previous
//
#include <hip/hip_runtime.h>

#define B_    32
#define S_    577
#define HID_  768
#define NH_   12
#define HD_   64
#define SPAD  640
#define M_    (B_ * S_)    // 18464 = 577*32
#define NPRIME (3 * HID_)  // 2304

typedef __attribute__((ext_vector_type(8))) short short8;
typedef __attribute__((ext_vector_type(4))) short short4_;
typedef __attribute__((ext_vector_type(4))) float float4_;

static __device__ __forceinline__ float bf2f(short s) {
    union { float f; unsigned u; } cvt;
    cvt.u = ((unsigned)(unsigned short)s) << 16;
    return cvt.f;
}
static __device__ __forceinline__ short f2bf(float f) {
    union { float f; unsigned u; } cvt;
    cvt.f = f;
    unsigned u = cvt.u;
    unsigned r = u + 0x7FFF + ((u >> 16) & 1);   // RNE; finite inputs
    return (short)(r >> 16);
}
// async global->LDS, 16B per lane; dest = wave-uniform base + lane*16
static __device__ __forceinline__ void gl_lds16(const short* g, short* l) {
    __builtin_amdgcn_global_load_lds(
        (const __attribute__((address_space(1))) unsigned int*)g,
        (__attribute__((address_space(3))) unsigned int*)l,
        16, 0, 0);
}

// ---------------------------------------------------------------------------
// fp32 -> bf16 converters
// ---------------------------------------------------------------------------
__global__ __launch_bounds__(256) void convw_kernel(
    const float* __restrict__ Wq, const float* __restrict__ Wk,
    const float* __restrict__ Wv, short* __restrict__ wbf)
{
    const int z = blockIdx.y;
    const float* W = (z == 0) ? Wq : (z == 1) ? Wk : Wv;
    const size_t idx = ((size_t)blockIdx.x * 256 + threadIdx.x) * 4;
    float4_ f = *(const float4_*)(W + idx);
    short4_ s;
#pragma unroll
    for (int e = 0; e < 4; ++e) s[e] = f2bf(f[e]);
    *(short4_*)(wbf + (size_t)z * (HID_ * HID_) + idx) = s;
}

__global__ __launch_bounds__(256) void convx_kernel(
    const float* __restrict__ X, short* __restrict__ xbf)
{
    const size_t idx = ((size_t)blockIdx.x * 256 + threadIdx.x) * 8;
    float4_ f0 = *(const float4_*)(X + idx);
    float4_ f1 = *(const float4_*)(X + idx + 4);
    short8 s;
#pragma unroll
    for (int e = 0; e < 4; ++e) { s[e] = f2bf(f0[e]); s[e + 4] = f2bf(f1[e]); }
    *(short8*)(xbf + idx) = s;
}

// ---------------------------------------------------------------------------
// Fused QKV projection as one GEMM: C[M=18464][N'=2304] = Xbf @ Wbf^T.
// m97 structure: 128x128 tile, BK=64, global_load_lds width-16 staging,
// 2-barrier K-loop. LDS layout [kgroup][row][8] (conflict-free b128 reads).
// Epilogue: +bias, optional lateral mix, store q/k [B,NH,SPAD,64], v^T.
// grid = (18 ntiles, 145 mtiles), block 256 (4 waves, 2x2 of 64x64).
// ---------------------------------------------------------------------------
__global__ __launch_bounds__(256) void gemm_kernel(
    const short* __restrict__ xbf, const short* __restrict__ wbf,
    const float* __restrict__ bq, const float* __restrict__ bk,
    const float* __restrict__ bv,
    const float* __restrict__ lat, const int* __restrict__ mixw,
    short* __restrict__ qo, short* __restrict__ ko, short* __restrict__ vo)
{
    __shared__ __align__(16) short At[8192];   // [kg8][row128][8] = 16 KB
    __shared__ __align__(16) short Bt[8192];

    const int nt = blockIdx.x;
    const int mt = blockIdx.y;
    const int m0 = mt * 128;
    const int n0 = nt * 128;
    const int z   = n0 / HID_;           // whole tile in one matrix
    const int nz0 = n0 - z * HID_;

    const int tid  = threadIdx.x;
    const int wave = tid >> 6;
    const int lane = tid & 63;
    const int quad = lane >> 4;
    const int l16  = lane & 15;

    // staging: issue i (0..3): slot = i*256+tid -> row = tid&127, kg = i*2+(tid>>7)
    const int srow = tid & 127;
    const int skg  = tid >> 7;
    int arow = m0 + srow; if (arow >= M_) arow = M_ - 1;   // clamp pad rows
    const short* ag = xbf + (size_t)arow * HID_ + skg * 8;
    const short* bg = wbf + (size_t)z * (HID_ * HID_)
                          + (size_t)(nz0 + srow) * HID_ + skg * 8;

    float4_ acc[4][4] = {};
    const int r0 = (wave & 1) * 64 + l16;
    const int c0 = (wave >> 1) * 64 + l16;

    for (int kt = 0; kt < 12; ++kt) {
        const int kk = kt * 64;
        if (kt) __syncthreads();               // prev tile fully consumed
#pragma unroll
        for (int i = 0; i < 4; ++i) {
            gl_lds16(ag + kk + i * 16, At + (i * 256 + wave * 64) * 8);
            gl_lds16(bg + kk + i * 16, Bt + (i * 256 + wave * 64) * 8);
        }
        __syncthreads();                       // drains vmcnt before barrier
#pragma unroll
        for (int c = 0; c < 2; ++c) {
            const int kb = (c * 4 + quad) * 128;
            short8 af[4], bf[4];
#pragma unroll
            for (int mi = 0; mi < 4; ++mi)
                af[mi] = *(const short8*)(At + (kb + r0 + mi * 16) * 8);
#pragma unroll
            for (int g = 0; g < 4; ++g)
                bf[g] = *(const short8*)(Bt + (kb + c0 + g * 16) * 8);
#pragma unroll
            for (int mi = 0; mi < 4; ++mi)
#pragma unroll
                for (int g = 0; g < 4; ++g)
                    acc[mi][g] = __builtin_amdgcn_mfma_f32_16x16x32_bf16(
                        af[mi], bf[g], acc[mi][g], 0, 0, 0);
        }
    }

    const int mwv = *mixw;
    const float* bb = (z == 0) ? bq : (z == 1) ? bk : bv;
#pragma unroll
    for (int mi = 0; mi < 4; ++mi) {
#pragma unroll
        for (int i = 0; i < 4; ++i) {
            const int m = m0 + (wave & 1) * 64 + mi * 16 + quad * 4 + i;
            if (m >= M_) continue;
            const unsigned bidx = (unsigned)m / S_;
            const unsigned s    = (unsigned)m - bidx * S_;
#pragma unroll
            for (int g = 0; g < 4; ++g) {
                const int nz = nz0 + (wave >> 1) * 64 + g * 16 + l16;
                const int h = nz >> 6, d = nz & 63;
                float val = acc[mi][g][i] + bb[nz];
                if (z == mwv)
                    val *= lat[(((size_t)bidx * NH_ + h) * S_ + s) * HD_ + d];
                const short o = f2bf(val);
                if (z == 2) {
                    vo[(((size_t)bidx * NH_ + h) * HD_ + d) * SPAD + s] = o;
                } else {
                    short* dst = (z == 0) ? qo : ko;
                    dst[(((size_t)bidx * NH_ + h) * SPAD + s) * HD_ + d] = o;
                }
            }
        }
    }
}

// ---------------------------------------------------------------------------
// Flash attention, block-level K/V LDS staging (64-key chunks).
// grid = (384 bh, 10 qtiles of 64), block 256 (4 waves x 16 q-rows).
// ---------------------------------------------------------------------------
__global__ __launch_bounds__(256) void attn_kernel(
    const short* __restrict__ q, const short* __restrict__ k,
    const short* __restrict__ vt, float* __restrict__ out)
{
    __shared__ __align__(16) short Kt[4096];          // [kg8][key64][8] 8 KB
    __shared__ __align__(16) short Vt[4096];          // [kg8][d64][8]   8 KB
    __shared__ __align__(16) short pbuf[4][16][64];   // per-wave P  8 KB

    const int bh   = blockIdx.x;
    const int b    = bh / NH_;
    const int h    = bh - b * NH_;
    const int tid  = threadIdx.x;
    const int wave = tid >> 6;
    const int lane = tid & 63;
    const int quad = lane >> 4;
    const int l16  = lane & 15;
    const int q0   = blockIdx.y * 64 + wave * 16;

    const short* qp = q  + (size_t)bh * SPAD * HD_;
    const short* kp = k  + (size_t)bh * SPAD * HD_;
    const short* vp = vt + (size_t)bh * HD_ * SPAD;

    const short8 aq0 = *(const short8*)(qp + (size_t)(q0 + l16) * HD_ + quad * 8);
    const short8 aq1 = *(const short8*)(qp + (size_t)(q0 + l16) * HD_ + 32 + quad * 8);

    float m_i[4], l_i[4];
    float4_ O[4] = {};
#pragma unroll
    for (int i = 0; i < 4; ++i) { m_i[i] = -3.0e38f; l_i[i] = 0.0f; }

    for (int kc = 0; kc < 10; ++kc) {
        const int key0 = kc * 64;
        if (kc) __syncthreads();
#pragma unroll
        for (int i = 0; i < 2; ++i) {
            gl_lds16(kp + (size_t)(key0 + lane) * HD_ + (i * 4 + wave) * 8,
                     Kt + (i * 256 + wave * 64) * 8);
            gl_lds16(vp + (size_t)lane * SPAD + key0 + (i * 4 + wave) * 8,
                     Vt + (i * 256 + wave * 64) * 8);
        }
        __syncthreads();

        // QK^T: sc[g] over 4 key-groups of 16
        float4_ sc[4] = {};
#pragma unroll
        for (int c = 0; c < 2; ++c) {
            const int kb = (c * 4 + quad) * 64;
            const short8 aq = c ? aq1 : aq0;
#pragma unroll
            for (int g = 0; g < 4; ++g) {
                short8 bk8 = *(const short8*)(Kt + (kb + g * 16 + l16) * 8);
                sc[g] = __builtin_amdgcn_mfma_f32_16x16x32_bf16(aq, bk8, sc[g], 0, 0, 0);
            }
        }

        float kmask[4];
#pragma unroll
        for (int g = 0; g < 4; ++g)
            kmask[g] = (key0 + g * 16 + l16 < S_) ? 0.0f : -3.0e38f;

        float alpha[4];
#pragma unroll
        for (int i = 0; i < 4; ++i) {
            float s0 = sc[0][i] * 0.125f + kmask[0];
            float s1 = sc[1][i] * 0.125f + kmask[1];
            float s2 = sc[2][i] * 0.125f + kmask[2];
            float s3 = sc[3][i] * 0.125f + kmask[3];
            float cm = fmaxf(fmaxf(s0, s1), fmaxf(s2, s3));
#pragma unroll
            for (int off = 1; off < 16; off <<= 1)
                cm = fmaxf(cm, __shfl_xor(cm, off));
            const float mn = fmaxf(m_i[i], cm);
            alpha[i] = __expf(m_i[i] - mn);
            m_i[i] = mn;
            const short p0 = f2bf(__expf(s0 - mn));
            const short p1 = f2bf(__expf(s1 - mn));
            const short p2 = f2bf(__expf(s2 - mn));
            const short p3 = f2bf(__expf(s3 - mn));
            pbuf[wave][quad * 4 + i][l16]      = p0;
            pbuf[wave][quad * 4 + i][l16 + 16] = p1;
            pbuf[wave][quad * 4 + i][l16 + 32] = p2;
            pbuf[wave][quad * 4 + i][l16 + 48] = p3;
            float rs = (bf2f(p0) + bf2f(p1)) + (bf2f(p2) + bf2f(p3));
#pragma unroll
            for (int off = 1; off < 16; off <<= 1)
                rs += __shfl_xor(rs, off);
            l_i[i] = l_i[i] * alpha[i] + rs;
        }

#pragma unroll
        for (int g = 0; g < 4; ++g)
#pragma unroll
            for (int i = 0; i < 4; ++i) O[g][i] *= alpha[i];

        // PV
#pragma unroll
        for (int c = 0; c < 2; ++c) {
            const short8 ap = *(const short8*)(&pbuf[wave][l16][c * 32 + quad * 8]);
            const int kb = (c * 4 + quad) * 64;
#pragma unroll
            for (int g = 0; g < 4; ++g) {
                short8 bv8 = *(const short8*)(Vt + (kb + g * 16 + l16) * 8);
                O[g] = __builtin_amdgcn_mfma_f32_16x16x32_bf16(ap, bv8, O[g], 0, 0, 0);
            }
        }
    }

#pragma unroll
    for (int i = 0; i < 4; ++i) {
        const int s = q0 + quad * 4 + i;
        if (s >= S_) continue;
        const float inv = 1.0f / l_i[i];
#pragma unroll
        for (int g = 0; g < 4; ++g)
            out[((size_t)b * S_ + s) * HID_ + h * HD_ + g * 16 + l16] = O[g][i] * inv;
    }
}

extern "C" void kernel_launch(void* const* d_in, const int* in_sizes, int n_in,
                              void* d_out, int out_size, void* d_ws, size_t ws_size,
                              hipStream_t stream) {
    (void)in_sizes; (void)n_in; (void)out_size; (void)ws_size;

    const float* X   = (const float*)d_in[0];
    const float* lat = (const float*)d_in[1];
    const float* Wq  = (const float*)d_in[2];
    const float* bq  = (const float*)d_in[3];
    const float* Wk  = (const float*)d_in[4];
    const float* bk  = (const float*)d_in[5];
    const float* Wv  = (const float*)d_in[6];
    const float* bv  = (const float*)d_in[7];
    const int* mixw  = (const int*)d_in[8];
    float* out = (float*)d_out;

    const size_t per = (size_t)B_ * NH_ * SPAD * HD_;   // 15,728,640
    short* qw  = (short*)d_ws;
    short* kw  = qw + per;
    short* vw  = kw + per;
    short* wbf = vw + per;                              // 1,769,472
    short* xbf = wbf + (size_t)3 * HID_ * HID_;         // 14,180,352

    convw_kernel<<<dim3(576, 3), 256, 0, stream>>>(Wq, Wk, Wv, wbf);
    convx_kernel<<<6924, 256, 0, stream>>>(X, xbf);
    gemm_kernel<<<dim3(18, 145), 256, 0, stream>>>(
        xbf, wbf, bq, bk, bv, lat, mixw, qw, kw, vw);
    attn_kernel<<<dim3(384, 10), 256, 0, stream>>>(qw, kw, vw, out);
}

// Round 4
// 499.422 us; speedup vs baseline: 2.1523x; 1.1754x over previous
//
#include <hip/hip_runtime.h>

#define B_    32
#define S_    577
#define HID_  768
#define NH_   12
#define HD_   64
#define SPAD  640
#define M_    (B_ * S_)    // 18464
#define MT_   145          // ceil(M/128)
#define KT_   12           // 768/64
#define NT_   18           // 2304/128

typedef __attribute__((ext_vector_type(8))) short short8;
typedef __attribute__((ext_vector_type(4))) float float4_;

static __device__ __forceinline__ float bf2f(short s) {
    union { float f; unsigned u; } cvt;
    cvt.u = ((unsigned)(unsigned short)s) << 16;
    return cvt.f;
}
static __device__ __forceinline__ short f2bf(float f) {
    union { float f; unsigned u; } cvt;
    cvt.f = f;
    unsigned u = cvt.u;
    unsigned r = u + 0x7FFF + ((u >> 16) & 1);   // RNE; finite inputs
    return (short)(r >> 16);
}
// async global->LDS: per-lane 16B from g(lane), written to ldsbase + lane*16
static __device__ __forceinline__ void gl_lds16(const short* g, short* l) {
    __builtin_amdgcn_global_load_lds(
        (const __attribute__((address_space(1))) unsigned int*)g,
        (__attribute__((address_space(3))) unsigned int*)l,
        16, 0, 0);
}

// ---------------------------------------------------------------------------
// A image: ximg[mt][kt][kg8][row128][8]  (byte-exact LDS staging image)
// coalesced fp32 reads, 128B-chunk bf16 writes
// ---------------------------------------------------------------------------
__global__ __launch_bounds__(256) void convA_kernel(
    const float* __restrict__ X, short* __restrict__ ximg)
{
    const int mt = blockIdx.x, kt = blockIdx.y;
    short* img = ximg + ((size_t)mt * KT_ + kt) * 8192;
#pragma unroll
    for (int i = 0; i < 4; ++i) {
        const int j = i * 256 + threadIdx.x;   // 0..1023
        const int row = j >> 3, kg = j & 7;
        int m = mt * 128 + row; if (m >= M_) m = 0;   // pad rows: any finite
        const float* src = X + (size_t)m * HID_ + kt * 64 + kg * 8;
        float4_ f0 = *(const float4_*)src;
        float4_ f1 = *(const float4_*)(src + 4);
        short8 s8;
#pragma unroll
        for (int e = 0; e < 4; ++e) { s8[e] = f2bf(f0[e]); s8[e + 4] = f2bf(f1[e]); }
        *(short8*)(img + ((size_t)kg * 128 + row) * 8) = s8;
    }
}

// B image: wimg[nt18][kt][kg8][row128][8], nt = z*6 + local (row = n in tile)
__global__ __launch_bounds__(256) void convB_kernel(
    const float* __restrict__ Wq, const float* __restrict__ Wk,
    const float* __restrict__ Wv, short* __restrict__ wimg)
{
    const int nt = blockIdx.x, kt = blockIdx.y;
    const int z = nt / 6;
    const float* W = (z == 0) ? Wq : (z == 1) ? Wk : Wv;
    const int n0 = (nt - z * 6) * 128;
    short* img = wimg + ((size_t)nt * KT_ + kt) * 8192;
#pragma unroll
    for (int i = 0; i < 4; ++i) {
        const int j = i * 256 + threadIdx.x;
        const int row = j >> 3, kg = j & 7;
        const float* src = W + (size_t)(n0 + row) * HID_ + kt * 64 + kg * 8;
        float4_ f0 = *(const float4_*)src;
        float4_ f1 = *(const float4_*)(src + 4);
        short8 s8;
#pragma unroll
        for (int e = 0; e < 4; ++e) { s8[e] = f2bf(f0[e]); s8[e + 4] = f2bf(f1[e]); }
        *(short8*)(img + ((size_t)kg * 128 + row) * 8) = s8;
    }
}

// ---------------------------------------------------------------------------
// Fused QKV GEMM, m97 structure, fully-coalesced global_load_lds staging.
// grid = (18 nt, 145 mt), block 256 (4 waves, 2x2 of 64x64).
// Outputs: q [bh][SPAD][64]; k image [bh][chunk10][kg8][key64][8];
//          v image [bh][chunk10][kg8][d64][8] (V^T chunks).
// ---------------------------------------------------------------------------
__global__ __launch_bounds__(256) void gemm_kernel(
    const short* __restrict__ ximg, const short* __restrict__ wimg,
    const float* __restrict__ bq, const float* __restrict__ bk,
    const float* __restrict__ bv,
    const float* __restrict__ lat, const int* __restrict__ mixw,
    short* __restrict__ qo, short* __restrict__ ko, short* __restrict__ vo)
{
    __shared__ __align__(16) short At[8192];   // [kg8][row128][8] = 16 KB
    __shared__ __align__(16) short Bt[8192];

    const int nt = blockIdx.x;
    const int mt = blockIdx.y;
    const int m0 = mt * 128;
    const int z   = nt / 6;
    const int nz0 = (nt - z * 6) * 128;

    const int tid  = threadIdx.x;
    const int wave = tid >> 6;
    const int lane = tid & 63;
    const int quad = lane >> 4;
    const int l16  = lane & 15;

    const short* ag = ximg + ((size_t)mt * KT_) * 8192;
    const short* bg = wimg + ((size_t)nt * KT_) * 8192;

    float4_ acc[4][4] = {};
    const int r0 = (wave & 1) * 64 + l16;
    const int c0 = (wave >> 1) * 64 + l16;

    for (int kt = 0; kt < KT_; ++kt) {
        if (kt) __syncthreads();
#pragma unroll
        for (int i = 0; i < 4; ++i) {
            // source contiguous: lane ℓ reads slot (i*256 + wave*64 + ℓ)
            gl_lds16(ag + (size_t)kt * 8192 + (i * 256 + tid) * 8,
                     At + (i * 256 + wave * 64) * 8);
            gl_lds16(bg + (size_t)kt * 8192 + (i * 256 + tid) * 8,
                     Bt + (i * 256 + wave * 64) * 8);
        }
        __syncthreads();
#pragma unroll
        for (int c = 0; c < 2; ++c) {
            const int kb = (c * 4 + quad) * 128;
            short8 af[4], bf[4];
#pragma unroll
            for (int mi = 0; mi < 4; ++mi)
                af[mi] = *(const short8*)(At + (kb + r0 + mi * 16) * 8);
#pragma unroll
            for (int g = 0; g < 4; ++g)
                bf[g] = *(const short8*)(Bt + (kb + c0 + g * 16) * 8);
#pragma unroll
            for (int mi = 0; mi < 4; ++mi)
#pragma unroll
                for (int g = 0; g < 4; ++g)
                    acc[mi][g] = __builtin_amdgcn_mfma_f32_16x16x32_bf16(
                        af[mi], bf[g], acc[mi][g], 0, 0, 0);
        }
    }

    const int mwv = *mixw;
    const float* bb = (z == 0) ? bq : (z == 1) ? bk : bv;
#pragma unroll
    for (int mi = 0; mi < 4; ++mi) {
#pragma unroll
        for (int i = 0; i < 4; ++i) {
            const int m = m0 + (wave & 1) * 64 + mi * 16 + quad * 4 + i;
            if (m >= M_) continue;
            const unsigned bidx = (unsigned)m / S_;
            const unsigned s    = (unsigned)m - bidx * S_;
#pragma unroll
            for (int g = 0; g < 4; ++g) {
                const int nz = nz0 + (wave >> 1) * 64 + g * 16 + l16;
                const int h = nz >> 6, d = nz & 63;
                float val = acc[mi][g][i] + bb[nz];
                if (z == mwv)
                    val *= lat[(((size_t)bidx * NH_ + h) * S_ + s) * HD_ + d];
                const short o = f2bf(val);
                const size_t bh = (size_t)bidx * NH_ + h;
                if (z == 0) {
                    qo[(bh * SPAD + s) * HD_ + d] = o;
                } else if (z == 1) {
                    ko[((bh * 10 + (s >> 6)) * 512 + (d >> 3) * 64 + (s & 63)) * 8
                       + (d & 7)] = o;
                } else {
                    vo[((bh * 10 + (s >> 6)) * 512 + ((s & 63) >> 3) * 64 + d) * 8
                       + (s & 7)] = o;
                }
            }
        }
    }
}

// ---------------------------------------------------------------------------
// Flash attention, block-level K/V LDS staging from pre-swizzled chunk images.
// grid = (384 bh, 10 qtiles of 64), block 256 (4 waves x 16 q-rows).
// ---------------------------------------------------------------------------
__global__ __launch_bounds__(256) void attn_kernel(
    const short* __restrict__ q, const short* __restrict__ k,
    const short* __restrict__ vt, float* __restrict__ out)
{
    __shared__ __align__(16) short Kt[4096];          // [kg8][key64][8] 8 KB
    __shared__ __align__(16) short Vt[4096];          // [kg8][d64][8]   8 KB
    __shared__ __align__(16) short pbuf[4][16][64];   // per-wave P      8 KB

    const int bh   = blockIdx.x;
    const int b    = bh / NH_;
    const int h    = bh - b * NH_;
    const int tid  = threadIdx.x;
    const int wave = tid >> 6;
    const int lane = tid & 63;
    const int quad = lane >> 4;
    const int l16  = lane & 15;
    const int q0   = blockIdx.y * 64 + wave * 16;

    const short* qp   = q  + (size_t)bh * SPAD * HD_;
    const short* kimg = k  + (size_t)bh * 40960;
    const short* vimg = vt + (size_t)bh * 40960;

    const short8 aq0 = *(const short8*)(qp + (size_t)(q0 + l16) * HD_ + quad * 8);
    const short8 aq1 = *(const short8*)(qp + (size_t)(q0 + l16) * HD_ + 32 + quad * 8);

    float m_i[4], l_i[4];
    float4_ O[4] = {};
#pragma unroll
    for (int i = 0; i < 4; ++i) { m_i[i] = -3.0e38f; l_i[i] = 0.0f; }

    for (int kc = 0; kc < 10; ++kc) {
        const int key0 = kc * 64;
        if (kc) __syncthreads();
#pragma unroll
        for (int i = 0; i < 2; ++i) {
            gl_lds16(kimg + (size_t)kc * 4096 + (i * 256 + tid) * 8,
                     Kt + (i * 256 + wave * 64) * 8);
            gl_lds16(vimg + (size_t)kc * 4096 + (i * 256 + tid) * 8,
                     Vt + (i * 256 + wave * 64) * 8);
        }
        __syncthreads();

        float4_ sc[4] = {};
#pragma unroll
        for (int c = 0; c < 2; ++c) {
            const int kb = (c * 4 + quad) * 64;
            const short8 aq = c ? aq1 : aq0;
#pragma unroll
            for (int g = 0; g < 4; ++g) {
                short8 bk8 = *(const short8*)(Kt + (kb + g * 16 + l16) * 8);
                sc[g] = __builtin_amdgcn_mfma_f32_16x16x32_bf16(aq, bk8, sc[g], 0, 0, 0);
            }
        }

        float kmask[4];
#pragma unroll
        for (int g = 0; g < 4; ++g)
            kmask[g] = (key0 + g * 16 + l16 < S_) ? 0.0f : -3.0e38f;

        float alpha[4];
#pragma unroll
        for (int i = 0; i < 4; ++i) {
            float s0 = sc[0][i] * 0.125f + kmask[0];
            float s1 = sc[1][i] * 0.125f + kmask[1];
            float s2 = sc[2][i] * 0.125f + kmask[2];
            float s3 = sc[3][i] * 0.125f + kmask[3];
            float cm = fmaxf(fmaxf(s0, s1), fmaxf(s2, s3));
#pragma unroll
            for (int off = 1; off < 16; off <<= 1)
                cm = fmaxf(cm, __shfl_xor(cm, off));
            const float mn = fmaxf(m_i[i], cm);
            alpha[i] = __expf(m_i[i] - mn);
            m_i[i] = mn;
            const short p0 = f2bf(__expf(s0 - mn));
            const short p1 = f2bf(__expf(s1 - mn));
            const short p2 = f2bf(__expf(s2 - mn));
            const short p3 = f2bf(__expf(s3 - mn));
            pbuf[wave][quad * 4 + i][l16]      = p0;
            pbuf[wave][quad * 4 + i][l16 + 16] = p1;
            pbuf[wave][quad * 4 + i][l16 + 32] = p2;
            pbuf[wave][quad * 4 + i][l16 + 48] = p3;
            float rs = (bf2f(p0) + bf2f(p1)) + (bf2f(p2) + bf2f(p3));
#pragma unroll
            for (int off = 1; off < 16; off <<= 1)
                rs += __shfl_xor(rs, off);
            l_i[i] = l_i[i] * alpha[i] + rs;
        }

#pragma unroll
        for (int g = 0; g < 4; ++g)
#pragma unroll
            for (int i = 0; i < 4; ++i) O[g][i] *= alpha[i];

#pragma unroll
        for (int c = 0; c < 2; ++c) {
            const short8 ap = *(const short8*)(&pbuf[wave][l16][c * 32 + quad * 8]);
            const int kb = (c * 4 + quad) * 64;
#pragma unroll
            for (int g = 0; g < 4; ++g) {
                short8 bv8 = *(const short8*)(Vt + (kb + g * 16 + l16) * 8);
                O[g] = __builtin_amdgcn_mfma_f32_16x16x32_bf16(ap, bv8, O[g], 0, 0, 0);
            }
        }
    }

#pragma unroll
    for (int i = 0; i < 4; ++i) {
        const int s = q0 + quad * 4 + i;
        if (s >= S_) continue;
        const float inv = 1.0f / l_i[i];
#pragma unroll
        for (int g = 0; g < 4; ++g)
            out[((size_t)b * S_ + s) * HID_ + h * HD_ + g * 16 + l16] = O[g][i] * inv;
    }
}

extern "C" void kernel_launch(void* const* d_in, const int* in_sizes, int n_in,
                              void* d_out, int out_size, void* d_ws, size_t ws_size,
                              hipStream_t stream) {
    (void)in_sizes; (void)n_in; (void)out_size; (void)ws_size;

    const float* X   = (const float*)d_in[0];
    const float* lat = (const float*)d_in[1];
    const float* Wq  = (const float*)d_in[2];
    const float* bq  = (const float*)d_in[3];
    const float* Wk  = (const float*)d_in[4];
    const float* bk  = (const float*)d_in[5];
    const float* Wv  = (const float*)d_in[6];
    const float* bv  = (const float*)d_in[7];
    const int* mixw  = (const int*)d_in[8];
    float* out = (float*)d_out;

    const size_t per = (size_t)B_ * NH_ * SPAD * HD_;   // 15,728,640
    short* qw   = (short*)d_ws;
    short* kw   = qw + per;
    short* vw   = kw + per;
    short* wimg = vw + per;                             // 18*12*8192 = 1,769,472
    short* ximg = wimg + (size_t)NT_ * KT_ * 8192;      // 145*12*8192 = 14,254,080

    convA_kernel<<<dim3(MT_, KT_), 256, 0, stream>>>(X, ximg);
    convB_kernel<<<dim3(NT_, KT_), 256, 0, stream>>>(Wq, Wk, Wv, wimg);
    gemm_kernel<<<dim3(NT_, MT_), 256, 0, stream>>>(
        ximg, wimg, bq, bk, bv, lat, mixw, qw, kw, vw);
    attn_kernel<<<dim3(384, 10), 256, 0, stream>>>(qw, kw, vw, out);
}